// Round 1
// 818.992 us; speedup vs baseline: 1.0175x; 1.0175x over previous
//
#include <hip/hip_runtime.h>
#include <hip/hip_bf16.h>

typedef __attribute__((ext_vector_type(8))) short short8;
typedef __attribute__((ext_vector_type(4))) float floatx4;
typedef __attribute__((ext_vector_type(4))) unsigned short ushort4v;
typedef __attribute__((ext_vector_type(8))) unsigned short ushort8v;

#define N_DIM 12288
#define SPLITK 4
#define KCHUNK (N_DIM / SPLITK)   // 3072
#define KSTEP 64
#define KITERS (KCHUNK / KSTEP)   // 48
#define NTILE 64

__device__ __forceinline__ unsigned short f2bf(float f) {
  union { float f; unsigned int i; } x; x.f = f;
  unsigned int r = x.i + 0x7fffu + ((x.i >> 16) & 1u);   // RNE
  return (unsigned short)(r >> 16);
}

// ---------------------------------------------------------------------------
// Kernel 1: phi_part[s] = obs[64 x Kchunk_s] @ W[Kchunk_s x 12288] (+bias s==0)
// fp32 inputs, on-the-fly bf16 conversion, 16x16x32 bf16 MFMA.
// v2: double-buffered LDS, ONE barrier per K-step, next-tile loads prefetched
// into regs during the MFMA phase; split-K partials plain-stored (no atomics,
// no memset) and summed by vin_mlp. grid=(192,4), block=256 (4 waves).
// ---------------------------------------------------------------------------
__global__ __launch_bounds__(256) void gemm_phi(
    const float* __restrict__ obs, const float* __restrict__ W,
    const float* __restrict__ bias, float* __restrict__ phi_part)
{
  __shared__ unsigned short A_s[2][64 * 72];   // [buf][m][k], stride 72
  __shared__ unsigned short W_s[2][64 * 72];   // [buf][n][k] (transposed)

  const int t = threadIdx.x;
  const int n0 = blockIdx.x * NTILE;
  const int s  = blockIdx.y;
  const int k0 = s * KCHUNK;
  const int lane = t & 63, wv = t >> 6;
  const int l16 = lane & 15, q = lane >> 4;
  const int m0f = 16 * wv;

  const int am = t >> 2, akq = (t & 3) * 16;   // A staging: row, 16-col group
  const int rg = t >> 4, cg = t & 15;          // W staging: 4-row group, 4-col group

  const float* aptr = obs + (size_t)am * N_DIM + k0 + akq;
  const float* wptr = W + (size_t)(k0 + 4 * rg) * N_DIM + (n0 + 4 * cg);

  floatx4 fa0, fa1, fa2, fa3, fw0, fw1, fw2, fw3;
#define LOAD_TILE(ap, wp) do {                                              \
    fa0 = *(const floatx4*)(ap);      fa1 = *(const floatx4*)((ap) + 4);    \
    fa2 = *(const floatx4*)((ap) + 8); fa3 = *(const floatx4*)((ap) + 12);  \
    fw0 = *(const floatx4*)(wp);              fw1 = *(const floatx4*)((wp) + N_DIM); \
    fw2 = *(const floatx4*)((wp) + 2 * N_DIM); fw3 = *(const floatx4*)((wp) + 3 * N_DIM); \
  } while (0)

  LOAD_TILE(aptr, wptr);   // prologue: tile 0 in flight

  floatx4 acc[4];
#pragma unroll
  for (int i = 0; i < 4; i++) acc[i] = (floatx4){0.f, 0.f, 0.f, 0.f};

  for (int it = 0; it < KITERS; ++it) {
    const int cur = it & 1;
    { // convert staged regs -> LDS[cur] (vmcnt wait happens here)
      ushort8v u0, u1;
#pragma unroll
      for (int i = 0; i < 4; i++) {
        u0[i] = f2bf(fa0[i]); u0[4 + i] = f2bf(fa1[i]);
        u1[i] = f2bf(fa2[i]); u1[4 + i] = f2bf(fa3[i]);
      }
      *(ushort8v*)&A_s[cur][am * 72 + akq]     = u0;
      *(ushort8v*)&A_s[cur][am * 72 + akq + 8] = u1;
#pragma unroll
      for (int i = 0; i < 4; i++) {
        ushort4v v = { f2bf(fw0[i]), f2bf(fw1[i]), f2bf(fw2[i]), f2bf(fw3[i]) };
        *(ushort4v*)&W_s[cur][(4 * cg + i) * 72 + 4 * rg] = v;
      }
    }
    if (it + 1 < KITERS) {   // prefetch next tile; consumed only next iteration
      const float* ap = aptr + (it + 1) * KSTEP;
      const float* wp = wptr + (size_t)(it + 1) * KSTEP * N_DIM;
      LOAD_TILE(ap, wp);
    }
    __syncthreads();   // LDS[cur] ready; also fences reads of LDS[cur^1] (prev MFMA)
#pragma unroll
    for (int kk = 0; kk < 2; ++kk) {
      // A frag: m = m0f+(lane&15), k = 32*kk + 8*(lane>>4) + j  [m89 layout]
      short8 af = *(const short8*)&A_s[cur][(m0f + l16) * 72 + 32 * kk + 8 * q];
#pragma unroll
      for (int nt = 0; nt < 4; ++nt) {
        short8 wf = *(const short8*)&W_s[cur][(16 * nt + l16) * 72 + 32 * kk + 8 * q];
        acc[nt] = __builtin_amdgcn_mfma_f32_16x16x32_bf16(af, wf, acc[nt], 0, 0, 0);
      }
    }
    // no trailing barrier: next iter writes LDS[cur^1]; any wave still reading
    // LDS[cur^1] is impossible past this iteration's barrier (2-buffer rotation)
  }

  // epilogue: C/D layout col=lane&15, row=(lane>>4)*4+r  [m89/m91]; plain stores
  float* dst = phi_part + (size_t)s * 64 * N_DIM;
#pragma unroll
  for (int nt = 0; nt < 4; ++nt) {
    const int ncol = n0 + 16 * nt + l16;
    const float bv = (s == 0) ? bias[ncol] : 0.f;
#pragma unroll
    for (int r = 0; r < 4; ++r) {
      const int m = m0f + q * 4 + r;
      dst[(size_t)m * N_DIM + ncol] = acc[nt][r] + bv;
    }
  }
#undef LOAD_TILE
}

// ---------------------------------------------------------------------------
// Kernel 2: per-batch softmax + K=64 VIN sweeps (ping-pong LDS) + argmax +
// patch + MLP. grid = 64 (one block per batch), block = 256 (4x4 cells/thread)
// v2: sums the 4 split-K partial phi buffers on load.
// ---------------------------------------------------------------------------
#define VSTR 76
#define VOFF(h, w) (((h) + 1) * VSTR + (w) + 4)  // halo grid, interior 16B-aligned

__global__ __launch_bounds__(256) void vin_mlp(
    const float* __restrict__ obs, const float* __restrict__ phi,
    const float* __restrict__ w1, const float* __restrict__ b1,
    const float* __restrict__ w2, const float* __restrict__ b2,
    float* __restrict__ out)
{
  __shared__ float Vb[2][66 * VSTR];
  __shared__ float red_v[256];
  __shared__ int   red_i[256];

  const int b = blockIdx.x;
  const int t = threadIdx.x;
  const int ty = t >> 4, tx = t & 15;
  const int h0 = ty * 4, w0 = tx * 4;

  // zero both V buffers (halo must stay 0; interior = V0 = 0)
  for (int i = t; i < 2 * 66 * VSTR; i += 256) (&Vb[0][0])[i] = 0.f;

  // read phi rows (sum 4 split-K partials) -> rin/rout/logits for own 16 cells
  float rin[16], rout[16], lg[16];
#pragma unroll
  for (int r = 0; r < 4; r++) {
    const int j = 3 * ((h0 + r) * 64 + w0);   // 12 contiguous floats, 16B-aligned
    const float* base = phi + (size_t)b * N_DIM + j;
    floatx4 x0 = *(const floatx4*)(base);
    floatx4 x1 = *(const floatx4*)(base + 4);
    floatx4 x2 = *(const floatx4*)(base + 8);
#pragma unroll
    for (int sp = 1; sp < SPLITK; sp++) {
      const float* bs = base + (size_t)sp * 64 * N_DIM;
      x0 += *(const floatx4*)(bs);
      x1 += *(const floatx4*)(bs + 4);
      x2 += *(const floatx4*)(bs + 8);
    }
    float f[12];
#pragma unroll
    for (int c = 0; c < 4; c++) { f[c] = x0[c]; f[4 + c] = x1[c]; f[8 + c] = x2[c]; }
#pragma unroll
    for (int c = 0; c < 4; c++) {
      rin [r * 4 + c] = f[3 * c + 0];
      rout[r * 4 + c] = f[3 * c + 1];
      lg  [r * 4 + c] = f[3 * c + 2];
    }
  }

  // block softmax over the 4096 logits
  float lmax = -3.4e38f;
#pragma unroll
  for (int i = 0; i < 16; i++) lmax = fmaxf(lmax, lg[i]);
  __syncthreads();                       // zero-fill done
  red_v[t] = lmax; __syncthreads();
  for (int o = 128; o > 0; o >>= 1) { if (t < o) red_v[t] = fmaxf(red_v[t], red_v[t + o]); __syncthreads(); }
  const float M = red_v[0];
  __syncthreads();
  float p[16]; float esum = 0.f;
#pragma unroll
  for (int i = 0; i < 16; i++) { p[i] = __expf(lg[i] - M); esum += p[i]; }
  red_v[t] = esum; __syncthreads();
  for (int o = 128; o > 0; o >>= 1) { if (t < o) red_v[t] += red_v[t + o]; __syncthreads(); }
  const float inv = 1.f / red_v[0];
  __syncthreads();
#pragma unroll
  for (int i = 0; i < 16; i++) p[i] *= inv;

  // stage rin into Vb[1] interior (halo stays 0) to get shifted-neighbor rin
#pragma unroll
  for (int r = 0; r < 4; r++) {
    floatx4 rr = { rin[r * 4 + 0], rin[r * 4 + 1], rin[r * 4 + 2], rin[r * 4 + 3] };
    *(floatx4*)&Vb[1][VOFF(h0 + r, w0)] = rr;
  }
  __syncthreads();
  // c_d = rin[nbr_d] - rout*(rin[nbr_d] != 0); constant across sweeps
  float cu[16], cdn[16], cl[16], cr[16];
#pragma unroll
  for (int r = 0; r < 4; r++) {
#pragma unroll
    for (int c = 0; c < 4; c++) {
      const int i = r * 4 + c, h = h0 + r, w = w0 + c;
      const float nu = Vb[1][VOFF(h - 1, w)];
      const float nd = Vb[1][VOFF(h + 1, w)];
      const float nl = Vb[1][VOFF(h, w - 1)];
      const float nr = Vb[1][VOFF(h, w + 1)];
      cu [i] = nu - (nu != 0.f ? rout[i] : 0.f);
      cdn[i] = nd - (nd != 0.f ? rout[i] : 0.f);
      cl [i] = nl - (nl != 0.f ? rout[i] : 0.f);
      cr [i] = nr - (nr != 0.f ? rout[i] : 0.f);
    }
  }
  __syncthreads();   // all c_d reads of Vb[1] done before sweep 0 overwrites it

  float v[16];
#pragma unroll
  for (int i = 0; i < 16; i++) v[i] = 0.f;

  // K=64 Jacobi sweeps: V_new = max(V, max_d(p*V[nbr_d] + c_d)), ping-pong LDS
  for (int k = 0; k < 64; k++) {
    const float* Vc = Vb[k & 1];
    float* Vn = Vb[(k & 1) ^ 1];
    const floatx4 top = *(const floatx4*)&Vc[VOFF(h0 - 1, w0)];
    const floatx4 bot = *(const floatx4*)&Vc[VOFF(h0 + 4, w0)];
    float lf[4], rt[4];
#pragma unroll
    for (int r = 0; r < 4; r++) { lf[r] = Vc[VOFF(h0 + r, w0 - 1)]; rt[r] = Vc[VOFF(h0 + r, w0 + 4)]; }
    float nv[16];
#pragma unroll
    for (int r = 0; r < 4; r++) {
#pragma unroll
      for (int c = 0; c < 4; c++) {
        const int i = r * 4 + c;
        const float vu = (r == 0) ? top[c] : v[i - 4];
        const float vd = (r == 3) ? bot[c] : v[i + 4];
        const float vl = (c == 0) ? lf[r] : v[i - 1];
        const float vr = (c == 3) ? rt[r] : v[i + 1];
        const float m1 = fmaxf(fmaf(p[i], vu, cu[i]), fmaf(p[i], vd, cdn[i]));
        const float m2 = fmaxf(fmaf(p[i], vl, cl[i]), fmaf(p[i], vr, cr[i]));
        nv[i] = fmaxf(v[i], fmaxf(m1, m2));
      }
    }
#pragma unroll
    for (int r = 0; r < 4; r++) {
      floatx4 w4 = { nv[r * 4 + 0], nv[r * 4 + 1], nv[r * 4 + 2], nv[r * 4 + 3] };
      *(floatx4*)&Vn[VOFF(h0 + r, w0)] = w4;
    }
#pragma unroll
    for (int i = 0; i < 16; i++) v[i] = nv[i];
    __syncthreads();
  }
  // final V is in Vb[0] (k=63 wrote buffer 0)

  // argmax over obs channel 1 (first-occurrence tie-break = min index)
  float amax = -3.4e38f; int aidx = 0;
#pragma unroll
  for (int r = 0; r < 4; r++) {
#pragma unroll
    for (int c = 0; c < 4; c++) {
      const int cell = (h0 + r) * 64 + (w0 + c);
      const float val = obs[(size_t)b * N_DIM + 3 * cell + 1];
      if (val > amax) { amax = val; aidx = cell; }
    }
  }
  red_v[t] = amax; red_i[t] = aidx;
  __syncthreads();
  for (int o = 128; o > 0; o >>= 1) {
    if (t < o) {
      const float v2 = red_v[t + o]; const int i2 = red_i[t + o];
      if (v2 > red_v[t] || (v2 == red_v[t] && i2 < red_i[t])) { red_v[t] = v2; red_i[t] = i2; }
    }
    __syncthreads();
  }
  const int pos = red_i[0];
  const int pi = pos >> 6, pj = pos & 63;
  __syncthreads();

  // 3x3x4 patch (channels 0..2 = obs, 3 = V; zero-padded borders)
  if (t < 36) {
    const int di = t / 12, rem = t % 12, dj = rem / 4, c4 = rem & 3;
    const int hh = pi - 1 + di, ww = pj - 1 + dj;
    float pv;
    if (c4 < 3) {
      pv = (hh >= 0 && hh < 64 && ww >= 0 && ww < 64)
           ? obs[(size_t)b * N_DIM + 3 * (hh * 64 + ww) + c4] : 0.f;
    } else {
      pv = Vb[0][VOFF(hh, ww)];   // halo provides the zero padding
    }
    red_v[t] = pv;
  }
  __syncthreads();
  if (t < 16) {
    float a = b1[t];
#pragma unroll
    for (int j = 0; j < 36; j++) a = fmaf(red_v[j], w1[j * 16 + t], a);
    red_v[64 + t] = fmaxf(a, 0.f);
  }
  __syncthreads();
  if (t < 4) {
    float a = b2[t];
#pragma unroll
    for (int i = 0; i < 16; i++) a = fmaf(red_v[64 + i], w2[i * 4 + t], a);
    out[b * 4 + t] = a;
  }
}

extern "C" void kernel_launch(void* const* d_in, const int* in_sizes, int n_in,
                              void* d_out, int out_size, void* d_ws, size_t ws_size,
                              hipStream_t stream)
{
  (void)in_sizes; (void)n_in; (void)out_size; (void)ws_size;
  const float* obs  = (const float*)d_in[0];
  const float* phiw = (const float*)d_in[1];
  const float* phib = (const float*)d_in[2];
  const float* w1   = (const float*)d_in[3];
  const float* b1   = (const float*)d_in[4];
  const float* w2   = (const float*)d_in[5];
  const float* b2   = (const float*)d_in[6];
  float* phi = (float*)d_ws;            // 4 * 64 * 12288 fp32 = 12.6 MB scratch
  float* out = (float*)d_out;

  hipLaunchKernelGGL(gemm_phi, dim3(N_DIM / NTILE, SPLITK), dim3(256), 0, stream,
                     obs, phiw, phib, phi);
  hipLaunchKernelGGL(vin_mlp, dim3(64), dim3(256), 0, stream,
                     obs, phi, w1, b1, w2, b2, out);
}